// Round 7
// baseline (226.424 us; speedup 1.0000x reference)
//
#include <hip/hip_runtime.h>
#include <hip/hip_bf16.h>

#define BB 8
#define TT 2048
#define CC 512
#define DD 512
#define HH 8
#define DH 64

typedef __bf16 bf16x8 __attribute__((ext_vector_type(8)));
typedef __bf16 bf16x4 __attribute__((ext_vector_type(4)));
typedef float  f32x4  __attribute__((ext_vector_type(4)));

static __device__ __forceinline__ bf16x8 concat4(bf16x4 a, bf16x4 b) {
    bf16x8 r;
    #pragma unroll
    for (int i = 0; i < 4; ++i) { r[i] = a[i]; r[i + 4] = b[i]; }
    return r;
}

// async global->LDS, 16B per lane; lds base must be wave-uniform
static __device__ __forceinline__ void async_ld16(const void* g, void* l) {
    __builtin_amdgcn_global_load_lds(
        (const __attribute__((address_space(1))) void*)g,
        (__attribute__((address_space(3))) void*)l, 16, 0, 0);
}

// ---------------------------------------------------------------------------
// Kernel 1: LayerNorm + transpose (B,C,T) fp32 -> (B*T, C) bf16.
// ---------------------------------------------------------------------------
__global__ __launch_bounds__(256) void ln_kernel(
    const float* __restrict__ x, const float* __restrict__ gamma,
    const float* __restrict__ beta, __hip_bfloat16* __restrict__ h)
{
    const int b  = blockIdx.x >> 6;
    const int t0 = (blockIdx.x & 63) * 32;
    const int tid = threadIdx.x;
    const int tl = tid & 31;
    const int part = tid >> 5;

    const float* xb = x + (size_t)b * CC * TT;

    __shared__ float xs[512][32];    // 64 KB
    float sum = 0.f, sq = 0.f;
    #pragma unroll 8
    for (int ci = 0; ci < 64; ++ci) {
        int c = part * 64 + ci;
        float v = xb[(size_t)c * TT + t0 + tl];
        xs[c][tl] = v;
        sum += v; sq += v * v;
    }
    __shared__ float sA[8][32], sB[8][32];
    sA[part][tl] = sum; sB[part][tl] = sq;
    __syncthreads();
    __shared__ float s_mu[32], s_rstd[32];
    if (part == 0) {
        float s = 0.f, q = 0.f;
        for (int p = 0; p < 8; ++p) { s += sA[p][tl]; q += sB[p][tl]; }
        float mu  = s * (1.0f / 512.0f);
        float var = q * (1.0f / 512.0f) - mu * mu;
        s_mu[tl] = mu;
        s_rstd[tl] = rsqrtf(var + 1e-5f);
    }
    __syncthreads();

    const float mu = s_mu[tl], rstd = s_rstd[tl];
    __shared__ __hip_bfloat16 tileT[32][72];

    for (int chunk = 0; chunk < 8; ++chunk) {
        int cb = chunk * 64 + part * 8;
        #pragma unroll
        for (int j = 0; j < 8; ++j) {
            int c = cb + j;
            float nv = (xs[c][tl] - mu) * rstd * gamma[c] + beta[c];
            tileT[tl][part * 8 + j] = __float2bfloat16(nv);
        }
        __syncthreads();
        int cl = tid & 63, tw = tid >> 6;
        #pragma unroll
        for (int k = 0; k < 8; ++k) {
            int t = tw + k * 4;
            h[((size_t)(b * TT + t0 + t)) * CC + chunk * 64 + cl] = tileT[t][cl];
        }
        __syncthreads();
    }
}

// ---------------------------------------------------------------------------
// Kernel 2: weight prepack (all 4): w (K,N) fp32 -> wt (N,K) bf16
// ---------------------------------------------------------------------------
__global__ __launch_bounds__(256) void prepack_w4(
    const float* __restrict__ w0, const float* __restrict__ w1,
    const float* __restrict__ w2, const float* __restrict__ w3,
    __hip_bfloat16* __restrict__ o0, __hip_bfloat16* __restrict__ o1,
    __hip_bfloat16* __restrict__ o2, __hip_bfloat16* __restrict__ o3)
{
    const float* w; __hip_bfloat16* wt;
    switch (blockIdx.y) {
        case 0: w = w0; wt = o0; break;
        case 1: w = w1; wt = o1; break;
        case 2: w = w2; wt = o2; break;
        default: w = w3; wt = o3; break;
    }
    __shared__ float tile[32][33];
    const int bx = blockIdx.x & 15;
    const int by = blockIdx.x >> 4;
    const int lx = threadIdx.x & 31, ly = threadIdx.x >> 5;
    #pragma unroll
    for (int i = 0; i < 4; ++i) {
        int k = by * 32 + ly + i * 8;
        tile[ly + i * 8][lx] = w[(size_t)k * 512 + bx * 32 + lx];
    }
    __syncthreads();
    #pragma unroll
    for (int i = 0; i < 4; ++i) {
        int n = bx * 32 + ly + i * 8;
        wt[(size_t)n * 512 + by * 32 + lx] = __float2bfloat16(tile[lx][ly + i * 8]);
    }
}

// ---------------------------------------------------------------------------
// Kernel 3: fused QKV GEMM.  BK=64, XOR-swizzled global_load_lds staging.
// Q (pre-scaled by log2e/8), K -> (B,H,T,64) via per-wave eps transpose +
// bf16x4 stores;  V -> V^T (B,H,64,T) via direct bf16x4 stores (lane's 4
// consecutive tokens at fixed d are contiguous in the transposed layout).
// ---------------------------------------------------------------------------
__global__ __launch_bounds__(256) void qkv_gemm(
    const __hip_bfloat16* __restrict__ A,
    const __hip_bfloat16* __restrict__ wtq, const __hip_bfloat16* __restrict__ wtk,
    const __hip_bfloat16* __restrict__ wtv,
    const float* __restrict__ bq, const float* __restrict__ bk,
    const float* __restrict__ bv,
    __hip_bfloat16* __restrict__ qo, __hip_bfloat16* __restrict__ ko,
    __hip_bfloat16* __restrict__ vt)
{
    const int m0 = blockIdx.x * 128;
    const int n0 = blockIdx.y * 128;
    const __hip_bfloat16* WT; const float* bias; __hip_bfloat16* out;
    if (blockIdx.z == 0)      { WT = wtq; bias = bq; out = qo; }
    else if (blockIdx.z == 1) { WT = wtk; bias = bk; out = ko; }
    else                      { WT = wtv; bias = bv; out = vt; }
    const float sc = (blockIdx.z == 0) ? 0.18033688011112042f : 1.0f;
    const bool vswap = (blockIdx.z == 2);

    __shared__ __hip_bfloat16 As[128][64];
    __shared__ __hip_bfloat16 Bs[128][64];
    __shared__ float eps[4][16][20];

    const int tid = threadIdx.x;
    const int wave = tid >> 6, lane = tid & 63;
    const int quad = lane >> 4, l16 = lane & 15;
    const int wy = wave >> 1, wx = wave & 1;

    const int r8 = lane >> 3;            // 0..7 row within 8-row issue
    const int c8 = lane & 7;             // col group
    const int cg = (c8 ^ r8) * 8;        // swizzled global col offset (elems)

    f32x4 acc[4][4] = {};

    for (int kt = 0; kt < 512; kt += 64) {
        #pragma unroll
        for (int i = 0; i < 4; ++i) {
            int rbase = wave * 32 + i * 8;
            int row = rbase + r8;
            async_ld16(&A[(size_t)(m0 + row) * 512 + kt + cg], &As[rbase][0]);
            async_ld16(&WT[(size_t)(n0 + row) * 512 + kt + cg], &Bs[rbase][0]);
        }
        __syncthreads();
        #pragma unroll
        for (int kk = 0; kk < 2; ++kk) {
            const int xr = l16 & 7;
            bf16x8 af[4], bfr[4];
            #pragma unroll
            for (int mt = 0; mt < 4; ++mt)
                af[mt] = *reinterpret_cast<const bf16x8*>(
                    &As[wy * 64 + mt * 16 + l16][((kk * 4 + quad) ^ xr) * 8]);
            #pragma unroll
            for (int nt = 0; nt < 4; ++nt)
                bfr[nt] = *reinterpret_cast<const bf16x8*>(
                    &Bs[wx * 64 + nt * 16 + l16][((kk * 4 + quad) ^ xr) * 8]);
            #pragma unroll
            for (int mt = 0; mt < 4; ++mt)
                #pragma unroll
                for (int nt = 0; nt < 4; ++nt)
                    acc[mt][nt] = __builtin_amdgcn_mfma_f32_16x16x32_bf16(
                        af[mt], bfr[nt], acc[mt][nt], 0, 0, 0);
        }
        __syncthreads();
    }

    if (vswap) {
        // V: C row = t (quad*4+r), col = d (l16); 4 consecutive t contiguous
        // in (B,H,dh,T) -> direct bf16x4 stores.
        #pragma unroll
        for (int nt = 0; nt < 4; ++nt) {
            int n = n0 + wx * 64 + nt * 16 + l16;
            int hh = n >> 6, di = n & 63;
            float bval = bias[n];
            #pragma unroll
            for (int mt = 0; mt < 4; ++mt) {
                int m = m0 + wy * 64 + mt * 16 + quad * 4;
                int b = m >> 11, t = m & 2047;
                bf16x4 pk;
                #pragma unroll
                for (int r = 0; r < 4; ++r)
                    pk[r] = (__bf16)(acc[mt][nt][r] + bval);
                *reinterpret_cast<bf16x4*>(
                    &out[((size_t)((b * HH + hh) * DH + di)) * TT + t]) = pk;
            }
        }
    } else {
        // Q/K: per-wave eps transpose -> lane gets 4 contiguous dh at one t
        #pragma unroll
        for (int mt = 0; mt < 4; ++mt) {
            #pragma unroll
            for (int nt = 0; nt < 4; ++nt) {
                float bval = bias[n0 + wx * 64 + nt * 16 + l16];
                #pragma unroll
                for (int r = 0; r < 4; ++r)
                    eps[wave][quad * 4 + r][l16] = acc[mt][nt][r] + bval;
                // wave-synchronous (single wave): compiler inserts lgkmcnt
                f32x4 v4 = *reinterpret_cast<const f32x4*>(&eps[wave][l16][quad * 4]);
                int nb = n0 + wx * 64 + nt * 16 + quad * 4;
                int hh = nb >> 6, di = nb & 63;
                int m = m0 + wy * 64 + mt * 16 + l16;
                int b = m >> 11, t = m & 2047;
                bf16x4 pk;
                #pragma unroll
                for (int j = 0; j < 4; ++j)
                    pk[j] = (__bf16)(v4[j] * sc);
                *reinterpret_cast<bf16x4*>(
                    &out[((size_t)((b * HH + hh) * TT + t)) * DH + di]) = pk;
            }
        }
    }
}

// ---------------------------------------------------------------------------
// attn tile compute: S^T = K Q^T; P in-register; O^T += Vt P^T   (R4 verbatim)
// ---------------------------------------------------------------------------
static __device__ __forceinline__ void attn_tile(
    const __hip_bfloat16 (*Ksb)[72], const __hip_bfloat16 (*Vtsb)[72],
    int k0, int q0, int wave, int quad, int l16,
    const bf16x8 (&qf)[2][2], f32x4 (&o_acc)[4][2], float (&l_run)[2])
{
    f32x4 s[2][4];
    #pragma unroll
    for (int nt = 0; nt < 4; ++nt) {
        bf16x8 kf0 = *reinterpret_cast<const bf16x8*>(&Ksb[nt * 16 + l16][quad * 8]);
        bf16x8 kf1 = *reinterpret_cast<const bf16x8*>(&Ksb[nt * 16 + l16][32 + quad * 8]);
        #pragma unroll
        for (int mt = 0; mt < 2; ++mt) {
            f32x4 z = {};
            z = __builtin_amdgcn_mfma_f32_16x16x32_bf16(kf0, qf[mt][0], z, 0, 0, 0);
            z = __builtin_amdgcn_mfma_f32_16x16x32_bf16(kf1, qf[mt][1], z, 0, 0, 0);
            s[mt][nt] = z;
        }
    }
    bf16x4 pt[2][4];
    #pragma unroll
    for (int mt = 0; mt < 2; ++mt) {
        const int qrow = q0 + wave * 32 + mt * 16 + l16;
        const bool fullun = (k0 + 63 <= q0 + wave * 32 + mt * 16);
        float lsum = 0.f;
        #pragma unroll
        for (int nt = 0; nt < 4; ++nt) {
            #pragma unroll
            for (int r = 0; r < 4; ++r) {
                float p = __builtin_amdgcn_exp2f(s[mt][nt][r]);
                if (!fullun) {
                    int key = k0 + nt * 16 + quad * 4 + r;
                    if (key > qrow) p = 0.f;
                }
                lsum += p;
                pt[mt][nt][r] = (__bf16)p;
            }
        }
        l_run[mt] += lsum;
    }
    #pragma unroll
    for (int cp = 0; cp < 2; ++cp) {
        bf16x8 pfr[2];
        #pragma unroll
        for (int mt = 0; mt < 2; ++mt)
            pfr[mt] = concat4(pt[mt][cp * 2], pt[mt][cp * 2 + 1]);
        #pragma unroll
        for (int dt = 0; dt < 4; ++dt) {
            bf16x4 va = *reinterpret_cast<const bf16x4*>(
                &Vtsb[dt * 16 + l16][cp * 32 + quad * 4]);
            bf16x4 vb = *reinterpret_cast<const bf16x4*>(
                &Vtsb[dt * 16 + l16][cp * 32 + 16 + quad * 4]);
            bf16x8 vf = concat4(va, vb);
            #pragma unroll
            for (int mt = 0; mt < 2; ++mt)
                o_acc[dt][mt] = __builtin_amdgcn_mfma_f32_16x16x32_bf16(
                    vf, pfr[mt], o_acc[dt][mt], 0, 0, 0);
        }
    }
}

// ---------------------------------------------------------------------------
// Kernel 4: causal flash attention, pair-balanced, dbuf LDS + VGPR prefetch.
// Flat grid 512: bh = idx & 63, xi = idx >> 6  =>  XCD = idx%8 = bh%8, so all
// 8 xi-blocks of one bh share an XCD's L2 (K/V working set = 4 MB = L2).
// Compute identical to R4 (measured 69.8 us).
// ---------------------------------------------------------------------------
__global__ __launch_bounds__(256, 2) void attn_kernel(
    const __hip_bfloat16* __restrict__ Q, const __hip_bfloat16* __restrict__ K,
    const __hip_bfloat16* __restrict__ Vt, __hip_bfloat16* __restrict__ ctx)
{
    const int xi = blockIdx.x >> 6;
    const int bh = blockIdx.x & 63;
    const int q0h = (15 - xi) * 128;
    const int q0l = xi * 128;
    const __hip_bfloat16* Qb  = Q  + (size_t)bh * TT * DH;
    const __hip_bfloat16* Kb  = K  + (size_t)bh * TT * DH;
    const __hip_bfloat16* Vtb = Vt + (size_t)bh * DH * TT;

    const int tid = threadIdx.x, wave = tid >> 6, lane = tid & 63;
    const int quad = lane >> 4, l16 = lane & 15;

    __shared__ __hip_bfloat16 Ks[2][64][72];
    __shared__ __hip_bfloat16 Vts[2][64][72];

    bf16x8 qfh[2][2], qfl[2][2];
    #pragma unroll
    for (int mt = 0; mt < 2; ++mt) {
        int rh = q0h + wave * 32 + mt * 16 + l16;
        int rl = q0l + wave * 32 + mt * 16 + l16;
        #pragma unroll
        for (int st = 0; st < 2; ++st) {
            qfh[mt][st] = *reinterpret_cast<const bf16x8*>(
                &Qb[(size_t)rh * DH + st * 32 + quad * 8]);
            qfl[mt][st] = *reinterpret_cast<const bf16x8*>(
                &Qb[(size_t)rl * DH + st * 32 + quad * 8]);
        }
    }

    f32x4 oh[4][2] = {}, ol[4][2] = {};
    float lh[2] = {0.f, 0.f}, ll[2] = {0.f, 0.f};

    const int rr = tid >> 3;          // 0..31
    const int co = (tid & 7) * 8;

    bf16x8 kreg[2], vreg[2];
    #pragma unroll
    for (int i = 0; i < 2; ++i) {
        int r2 = rr + i * 32;
        kreg[i] = *reinterpret_cast<const bf16x8*>(&Kb[(size_t)r2 * DH + co]);
        vreg[i] = *reinterpret_cast<const bf16x8*>(&Vtb[(size_t)r2 * TT + co]);
    }
    #pragma unroll
    for (int i = 0; i < 2; ++i) {
        int r2 = rr + i * 32;
        *reinterpret_cast<bf16x8*>(&Ks[0][r2][co]) = kreg[i];
        *reinterpret_cast<bf16x8*>(&Vts[0][r2][co]) = vreg[i];
    }
    __syncthreads();

    const int nsteps = q0h / 64 + 2;
    for (int step = 0; step < nsteps; ++step) {
        const int k0 = step * 64;
        const int cur = step & 1;
        const bool havenext = (step + 1 < nsteps);
        if (havenext) {
            const int kn = k0 + 64;
            #pragma unroll
            for (int i = 0; i < 2; ++i) {
                int r2 = rr + i * 32;
                kreg[i] = *reinterpret_cast<const bf16x8*>(
                    &Kb[(size_t)(kn + r2) * DH + co]);
                vreg[i] = *reinterpret_cast<const bf16x8*>(
                    &Vtb[(size_t)r2 * TT + kn + co]);
            }
        }
        if (k0 <= q0h + wave * 32 + 31)
            attn_tile(Ks[cur], Vts[cur], k0, q0h, wave, quad, l16, qfh, oh, lh);
        if (k0 <= q0l + wave * 32 + 31)
            attn_tile(Ks[cur], Vts[cur], k0, q0l, wave, quad, l16, qfl, ol, ll);
        if (havenext) {
            const int nxt = cur ^ 1;
            #pragma unroll
            for (int i = 0; i < 2; ++i) {
                int r2 = rr + i * 32;
                *reinterpret_cast<bf16x8*>(&Ks[nxt][r2][co]) = kreg[i];
                *reinterpret_cast<bf16x8*>(&Vts[nxt][r2][co]) = vreg[i];
            }
        }
        __syncthreads();
    }

    float invh[2], invl[2];
    #pragma unroll
    for (int mt = 0; mt < 2; ++mt) {
        float a = lh[mt];
        a += __shfl_xor(a, 16, 64); a += __shfl_xor(a, 32, 64);
        invh[mt] = 1.0f / a;
        float c = ll[mt];
        c += __shfl_xor(c, 16, 64); c += __shfl_xor(c, 32, 64);
        invl[mt] = 1.0f / c;
    }

    const int b = bh >> 3, hh = bh & 7;
    #pragma unroll
    for (int mt = 0; mt < 2; ++mt) {
        int th = q0h + wave * 32 + mt * 16 + l16;
        int tl2 = q0l + wave * 32 + mt * 16 + l16;
        #pragma unroll
        for (int dt = 0; dt < 4; ++dt) {
            bf16x4 pa, pb;
            #pragma unroll
            for (int r = 0; r < 4; ++r) {
                pa[r] = (__bf16)(oh[dt][mt][r] * invh[mt]);
                pb[r] = (__bf16)(ol[dt][mt][r] * invl[mt]);
            }
            *reinterpret_cast<bf16x4*>(
                &ctx[((size_t)(b * TT + th)) * DD + hh * DH + dt * 16 + quad * 4]) = pa;
            *reinterpret_cast<bf16x4*>(
                &ctx[((size_t)(b * TT + tl2)) * DD + hh * DH + dt * 16 + quad * 4]) = pb;
        }
    }
}

// ---------------------------------------------------------------------------
// Kernel 5: out-proj, BK=64 + swizzled global_load_lds staging:
// D[c][t] = sum_d wto[c][d] * ctx[t][d];  out = x + D + bo (coalesced t).
// ---------------------------------------------------------------------------
__global__ __launch_bounds__(256) void oproj_gemm(
    const __hip_bfloat16* __restrict__ WT, const __hip_bfloat16* __restrict__ Actx,
    const float* __restrict__ bo, const float* __restrict__ xres,
    float* __restrict__ outp)
{
    const int m0 = blockIdx.x * 128;   // c tile
    const int n0 = blockIdx.y * 128;   // token tile

    __shared__ __hip_bfloat16 As[128][64];
    __shared__ __hip_bfloat16 Bs[128][64];

    const int tid = threadIdx.x;
    const int wave = tid >> 6, lane = tid & 63;
    const int quad = lane >> 4, l16 = lane & 15;
    const int wy = wave >> 1, wx = wave & 1;

    const int r8 = lane >> 3;
    const int c8 = lane & 7;
    const int cg = (c8 ^ r8) * 8;

    f32x4 acc[4][4] = {};

    for (int kt = 0; kt < 512; kt += 64) {
        #pragma unroll
        for (int i = 0; i < 4; ++i) {
            int rbase = wave * 32 + i * 8;
            int row = rbase + r8;
            async_ld16(&WT[(size_t)(m0 + row) * 512 + kt + cg], &As[rbase][0]);
            async_ld16(&Actx[(size_t)(n0 + row) * 512 + kt + cg], &Bs[rbase][0]);
        }
        __syncthreads();
        #pragma unroll
        for (int kk = 0; kk < 2; ++kk) {
            const int xr = l16 & 7;
            bf16x8 af[4], bfr[4];
            #pragma unroll
            for (int mt = 0; mt < 4; ++mt)
                af[mt] = *reinterpret_cast<const bf16x8*>(
                    &As[wy * 64 + mt * 16 + l16][((kk * 4 + quad) ^ xr) * 8]);
            #pragma unroll
            for (int nt = 0; nt < 4; ++nt)
                bfr[nt] = *reinterpret_cast<const bf16x8*>(
                    &Bs[wx * 64 + nt * 16 + l16][((kk * 4 + quad) ^ xr) * 8]);
            #pragma unroll
            for (int mt = 0; mt < 4; ++mt)
                #pragma unroll
                for (int nt = 0; nt < 4; ++nt)
                    acc[mt][nt] = __builtin_amdgcn_mfma_f32_16x16x32_bf16(
                        af[mt], bfr[nt], acc[mt][nt], 0, 0, 0);
        }
        __syncthreads();
    }

    #pragma unroll
    for (int mt = 0; mt < 4; ++mt) {
        #pragma unroll
        for (int nt = 0; nt < 4; ++nt) {
            int tg = n0 + wx * 64 + nt * 16 + l16;
            int b = tg >> 11, t = tg & 2047;
            #pragma unroll
            for (int r = 0; r < 4; ++r) {
                int c = m0 + wy * 64 + mt * 16 + quad * 4 + r;
                size_t oi = ((size_t)(b * CC + c)) * TT + t;
                outp[oi] = xres[oi] + acc[mt][nt][r] + bo[c];
            }
        }
    }
}

// ---------------------------------------------------------------------------
extern "C" void kernel_launch(void* const* d_in, const int* in_sizes, int n_in,
                              void* d_out, int out_size, void* d_ws, size_t ws_size,
                              hipStream_t stream)
{
    const float* x     = (const float*)d_in[0];
    const float* gamma = (const float*)d_in[1];
    const float* beta  = (const float*)d_in[2];
    const float* wq    = (const float*)d_in[3];
    const float* bq    = (const float*)d_in[4];
    const float* wk    = (const float*)d_in[5];
    const float* bk    = (const float*)d_in[6];
    const float* wv    = (const float*)d_in[7];
    const float* bv    = (const float*)d_in[8];
    const float* wo    = (const float*)d_in[9];
    const float* bo    = (const float*)d_in[10];
    float* out = (float*)d_out;

    char* ws = (char*)d_ws;
    const size_t sz_big = (size_t)BB * TT * DD * sizeof(__hip_bfloat16); // 16 MB
    __hip_bfloat16* hbf = (__hip_bfloat16*)ws; ws += sz_big;
    __hip_bfloat16* qb  = (__hip_bfloat16*)ws; ws += sz_big;
    __hip_bfloat16* kb  = (__hip_bfloat16*)ws; ws += sz_big;
    __hip_bfloat16* vtb = (__hip_bfloat16*)ws; ws += sz_big;
    __hip_bfloat16* ctx = (__hip_bfloat16*)ws; ws += sz_big;
    const size_t sz_w = (size_t)512 * 512 * sizeof(__hip_bfloat16);
    __hip_bfloat16* wtq = (__hip_bfloat16*)ws; ws += sz_w;
    __hip_bfloat16* wtk = (__hip_bfloat16*)ws; ws += sz_w;
    __hip_bfloat16* wtv = (__hip_bfloat16*)ws; ws += sz_w;
    __hip_bfloat16* wto = (__hip_bfloat16*)ws; ws += sz_w;

    prepack_w4<<<dim3(256, 4), 256, 0, stream>>>(wq, wk, wv, wo,
                                                 wtq, wtk, wtv, wto);

    ln_kernel<<<BB * (TT / 32), 256, 0, stream>>>(x, gamma, beta, hbf);

    qkv_gemm<<<dim3(BB * TT / 128, DD / 128, 3), 256, 0, stream>>>(
        hbf, wtq, wtk, wtv, bq, bk, bv, qb, kb, vtb);

    attn_kernel<<<dim3(512), 256, 0, stream>>>(qb, kb, vtb, ctx);

    oproj_gemm<<<dim3(CC / 128, BB * TT / 128), 256, 0, stream>>>(
        wto, ctx, bo, x, out);
}